// Round 4
// baseline (1190.912 us; speedup 1.0000x reference)
//
#include <hip/hip_runtime.h>
#include <hip/hip_bf16.h>

// ---------- types & helpers ----------
typedef __attribute__((ext_vector_type(8))) short short8;   // 8 bf16 (4 VGPRs)
typedef __attribute__((ext_vector_type(4))) float f32x4;

#define AS1 __attribute__((address_space(1)))
#define AS3 __attribute__((address_space(3)))

__device__ __forceinline__ void gload16(const void* g, void* l) {
  __builtin_amdgcn_global_load_lds((const AS1 unsigned int*)g,
                                   (AS3 unsigned int*)l, 16, 0, 0);
}

__device__ __forceinline__ unsigned short f2bf(float x) {
  unsigned u = __float_as_uint(x);
  u = (u + 0x7FFFu + ((u >> 16) & 1u)) >> 16;  // RNE
  return (unsigned short)u;
}

__device__ __forceinline__ short8 lds8(const unsigned short* p) {
  return *(const short8*)p;
}

// Swizzled 16B LDS read: logical (row, byteInRow) of a 128B-row tile.
// Swizzle: 16B-slot ^= row&7.
__device__ __forceinline__ short8 lds8s(const unsigned short* base, int row, int byteInRow) {
  const int a = (row << 7) + (byteInRow ^ ((row & 7) << 4));
  return *(const short8*)((const char*)base + a);
}

// Problem constants: L=S=2048, N=4, E=1024, H=16, D=64; rows = L*N = 8192
#define LL 2048
#define NB 4
#define EE 1024
#define HH 16
#define DD 64
#define MROWS 8192
#define SC2 0.18033688f  // 0.125 * log2(e): softmax in exp2 domain

// ---------- fp32 -> bf16 convert ----------
__global__ __launch_bounds__(256) void conv_bf16(const float* __restrict__ src,
                                                 unsigned short* __restrict__ dst) {
  int i = blockIdx.x * 256 + threadIdx.x;
  float4 v = ((const float4*)src)[i];
  ushort4 o;
  o.x = f2bf(v.x); o.y = f2bf(v.y); o.z = f2bf(v.z); o.w = f2bf(v.w);
  ((ushort4*)dst)[i] = o;
}

// ---------- GEMM: C[8192,1024] = A[8192,1024] * B[1024,1024]^T + bias ----------
// MODE 0: bf16 head layout [n,h,l,d]; MODE 1: bf16 transposed [n,h,d,s]; MODE 2: fp32 rows
template <int MODE>
__global__ __launch_bounds__(256) void gemm_bt(const unsigned short* __restrict__ A,
                                               const unsigned short* __restrict__ B,
                                               const float* __restrict__ bias,
                                               unsigned short* __restrict__ outb,
                                               float* __restrict__ outf) {
  constexpr int K = 1024;
  __shared__ __align__(16) unsigned short As[128 * 32];
  __shared__ __align__(16) unsigned short Bs[128 * 32];
  const int tid = threadIdx.x;
  const int lane = tid & 63, w = tid >> 6;
  const int wr = w >> 1, wc = w & 1;           // 2x2 waves, each 64x64
  const int lrow = lane & 15, lg = lane >> 4;
  const int m0 = blockIdx.y * 128, n0 = blockIdx.x * 128;

  f32x4 acc[4][4] = {};

  const int srow = tid >> 2, sseg = tid & 3;   // staging map: 64 rows x 4 16B-segs
  for (int k0 = 0; k0 < K; k0 += 32) {
    __syncthreads();
    const unsigned short* ga = A + (size_t)(m0 + srow) * K + k0 + sseg * 8;
    gload16(ga,            (char*)As + tid * 16);
    gload16(ga + 64 * K,   (char*)As + tid * 16 + 4096);
    const unsigned short* gb = B + (size_t)(n0 + srow) * K + k0 + sseg * 8;
    gload16(gb,            (char*)Bs + tid * 16);
    gload16(gb + 64 * K,   (char*)Bs + tid * 16 + 4096);
    __syncthreads();

    short8 af[4], bf[4];
#pragma unroll
    for (int mt = 0; mt < 4; ++mt)
      af[mt] = lds8(As + (wr * 64 + mt * 16 + lrow) * 32 + lg * 8);
#pragma unroll
    for (int nt = 0; nt < 4; ++nt)
      bf[nt] = lds8(Bs + (wc * 64 + nt * 16 + lrow) * 32 + lg * 8);
#pragma unroll
    for (int mt = 0; mt < 4; ++mt)
#pragma unroll
      for (int nt = 0; nt < 4; ++nt)
        acc[mt][nt] = __builtin_amdgcn_mfma_f32_16x16x32_bf16(af[mt], bf[nt],
                                                              acc[mt][nt], 0, 0, 0);
  }

#pragma unroll
  for (int mt = 0; mt < 4; ++mt) {
#pragma unroll
    for (int nt = 0; nt < 4; ++nt) {
      const int col = n0 + wc * 64 + nt * 16 + lrow;
      const float bv = bias[col];
#pragma unroll
      for (int r = 0; r < 4; ++r) {
        const int row = m0 + wr * 64 + mt * 16 + lg * 4 + r;  // token-row = l*4+n
        const float v = acc[mt][nt][r] + bv;
        if (MODE == 0) {
          const int l = row >> 2, n = row & 3, h = col >> 6, d = col & 63;
          outb[(((size_t)(n * HH + h)) * LL + l) * DD + d] = f2bf(v);
        } else if (MODE == 1) {
          const int s = row >> 2, n = row & 3, h = col >> 6, d = col & 63;
          outb[(((size_t)(n * HH + h)) * DD + d) * LL + s] = f2bf(v);
        } else {
          outf[(size_t)row * EE + col] = v;
        }
      }
    }
  }
}

// ---------- flash attention per (n,h): 64 q-rows per block ----------
// Swapped-operand MFMA: S^T = mfma(K,Q) puts per-lane q = lane&15 -> in-register
// softmax (2 shfls), vector P writes, O^T = mfma(V,P) matches per-lane m/z.
__global__ __launch_bounds__(256) void flash_attn(const unsigned short* __restrict__ qh,
                                                  const unsigned short* __restrict__ kh,
                                                  const unsigned short* __restrict__ vth,
                                                  unsigned short* __restrict__ oh,
                                                  float* __restrict__ mbuf,
                                                  float* __restrict__ zbuf) {
  __shared__ __align__(16) unsigned short Ks[2][64 * 64];
  __shared__ __align__(16) unsigned short Vts[2][64 * 64];
  __shared__ __align__(16) unsigned short QPs[64 * 64];  // Q tile, then reused as P tile
  const int tid = threadIdx.x, lane = tid & 63, w = tid >> 6;
  const int lrow = lane & 15, lg = lane >> 4;
  const int nh = blockIdx.y;
  const int l0 = blockIdx.x * 64;

  const unsigned short* qbase = qh + ((size_t)nh * LL + l0) * DD;
  const unsigned short* kbase = kh + (size_t)nh * LL * DD;
  const unsigned short* vbase = vth + (size_t)nh * DD * LL;

  const int sr = tid >> 3;                      // staging row 0..31 (and +32)
  const int cs = ((tid & 7) ^ (sr & 7)) * 8;    // pre-swizzled col (shorts)

  // stage Q + tile 0 of K/V
  gload16(qbase + (size_t)sr * DD + cs,        (char*)QPs + tid * 16);
  gload16(qbase + (size_t)(sr + 32) * DD + cs, (char*)QPs + tid * 16 + 4096);
  gload16(kbase + (size_t)sr * DD + cs,        (char*)Ks[0] + tid * 16);
  gload16(kbase + (size_t)(sr + 32) * DD + cs, (char*)Ks[0] + tid * 16 + 4096);
  gload16(vbase + (size_t)sr * LL + cs,        (char*)Vts[0] + tid * 16);
  gload16(vbase + (size_t)(sr + 32) * LL + cs, (char*)Vts[0] + tid * 16 + 4096);
  __syncthreads();

  // Q fragments -> registers; QPs rows (wave-private w*16..w*16+15) then free for P
  short8 qa0 = lds8s(QPs, w * 16 + lrow, lg * 16);
  short8 qa1 = lds8s(QPs, w * 16 + lrow, 64 + lg * 16);

  float mrow = -1e30f, zrow = 0.f;   // per-lane: this lane's q-row = l0 + w*16 + lrow
  f32x4 acco[4] = {};                // O[q=lrow][d = dt*16 + lg*4 + r]

  const int prow = w * 16 + lrow;
  int cur = 0;
  for (int s0 = 0; s0 < LL; s0 += 64) {
    // prefetch next K/V tile (overlaps compute; drained by end-of-iter barrier)
    if (s0 + 64 < LL) {
      const int nxt = cur ^ 1;
      const unsigned short* kt = kbase + (size_t)(s0 + 64) * DD;
      gload16(kt + (size_t)sr * DD + cs,        (char*)Ks[nxt] + tid * 16);
      gload16(kt + (size_t)(sr + 32) * DD + cs, (char*)Ks[nxt] + tid * 16 + 4096);
      gload16(vbase + (size_t)sr * LL + (s0 + 64) + cs,        (char*)Vts[nxt] + tid * 16);
      gload16(vbase + (size_t)(sr + 32) * LL + (s0 + 64) + cs, (char*)Vts[nxt] + tid * 16 + 4096);
    }

    // QK^T swapped: sc[ct] = S[q=lrow][k = ct*16 + lg*4 + r]
    f32x4 sc[4];
    __builtin_amdgcn_s_setprio(1);
#pragma unroll
    for (int ct = 0; ct < 4; ++ct) {
      short8 b0 = lds8s(Ks[cur], ct * 16 + lrow, lg * 16);
      short8 b1 = lds8s(Ks[cur], ct * 16 + lrow, 64 + lg * 16);
      f32x4 a = {};
      a = __builtin_amdgcn_mfma_f32_16x16x32_bf16(b0, qa0, a, 0, 0, 0);
      a = __builtin_amdgcn_mfma_f32_16x16x32_bf16(b1, qa1, a, 0, 0, 0);
      sc[ct] = a;
    }
    __builtin_amdgcn_s_setprio(0);

    // in-register row max (this lane's q) + 2 cross-lane shfls
    float t = sc[0][0];
#pragma unroll
    for (int ct = 0; ct < 4; ++ct)
#pragma unroll
      for (int r = 0; r < 4; ++r) t = fmaxf(t, sc[ct][r]);
    t = fmaxf(t, __shfl_xor(t, 16));
    t = fmaxf(t, __shfl_xor(t, 32));
    const float tm = t * SC2;

    if (__any(tm > mrow + 8.0f)) {     // deferred rescale
      const float mnew = fmaxf(mrow, tm);
      const float f = __builtin_exp2f(mrow - mnew);
      mrow = mnew;
      zrow *= f;
#pragma unroll
      for (int dt = 0; dt < 4; ++dt)
#pragma unroll
        for (int r = 0; r < 4; ++r) acco[dt][r] *= f;
    }

    // P = exp2(sc*SC2 - m); pack 4 bf16 per ct; one ds_write_b64 per ct
    float ps = 0.f;
    unsigned int pk[8];
#pragma unroll
    for (int ct = 0; ct < 4; ++ct) {
      float e[4];
#pragma unroll
      for (int r = 0; r < 4; ++r) {
        e[r] = __builtin_exp2f(__builtin_fmaf(sc[ct][r], SC2, -mrow));
        ps += e[r];
      }
      pk[ct * 2 + 0] = (unsigned int)f2bf(e[0]) | ((unsigned int)f2bf(e[1]) << 16);
      pk[ct * 2 + 1] = (unsigned int)f2bf(e[2]) | ((unsigned int)f2bf(e[3]) << 16);
    }
    ps += __shfl_xor(ps, 16);
    ps += __shfl_xor(ps, 32);
    zrow += ps;

#pragma unroll
    for (int ct = 0; ct < 4; ++ct) {
      const int a = (prow << 7) + ((((ct * 2 + (lg >> 1)) ^ (prow & 7)) << 4) | ((lg & 1) << 3));
      uint2 u; u.x = pk[ct * 2]; u.y = pk[ct * 2 + 1];
      *(uint2*)((char*)QPs + a) = u;
    }

    // PV swapped: acco[dt] += Vt_frag · P_frag  (O^T: q = lane&15 matches m/z)
    short8 pa0 = lds8s(QPs, prow, lg * 16);
    short8 pa1 = lds8s(QPs, prow, 64 + lg * 16);
    __builtin_amdgcn_s_setprio(1);
#pragma unroll
    for (int dt = 0; dt < 4; ++dt) {
      short8 vb0 = lds8s(Vts[cur], dt * 16 + lrow, lg * 16);
      short8 vb1 = lds8s(Vts[cur], dt * 16 + lrow, 64 + lg * 16);
      acco[dt] = __builtin_amdgcn_mfma_f32_16x16x32_bf16(vb0, pa0, acco[dt], 0, 0, 0);
      acco[dt] = __builtin_amdgcn_mfma_f32_16x16x32_bf16(vb1, pa1, acco[dt], 0, 0, 0);
    }
    __builtin_amdgcn_s_setprio(0);
    __syncthreads();   // staging drained + all reads of buf[cur] complete
    cur ^= 1;
  }

  const int n = nh >> 4, h = nh & 15;
  const int lt = l0 + w * 16 + lrow;
  const float rz = 1.0f / zrow;
#pragma unroll
  for (int dt = 0; dt < 4; ++dt) {
    ushort4 o;
    o.x = f2bf(acco[dt][0] * rz);
    o.y = f2bf(acco[dt][1] * rz);
    o.z = f2bf(acco[dt][2] * rz);
    o.w = f2bf(acco[dt][3] * rz);
    *(ushort4*)&oh[((size_t)lt * NB + n) * EE + h * 64 + dt * 16 + lg * 4] = o;
  }
  if (lg == 0) {
    mbuf[(size_t)nh * LL + lt] = mrow;   // exp2-domain running max
    zbuf[(size_t)nh * LL + lt] = zrow;
  }
}

// ---------- prep: cT[n][lt][h] = -(m + log2(z))  (weight = exp2(sc*SC2 + c)) ----------
__global__ __launch_bounds__(256) void mz_prep(const float* __restrict__ mbuf,
                                               const float* __restrict__ zbuf,
                                               float* __restrict__ cT) {
  const int i = blockIdx.x * 256 + threadIdx.x;   // over 64*2048
  const int nh = i >> 11, lt = i & 2047;
  const int n = nh >> 4, h = nh & 15;
  const float c = -(mbuf[i] + __builtin_log2f(zbuf[i]));
  cT[((size_t)n * LL + lt) * HH + h] = c;
}

// ---------- weights mean: out1[n][l][s] = (1/16) sum_h exp2(sc*SC2 + c_h) ----------
// Swapped QK^T, double-buffered heads via pointer-stride, c-tile in LDS,
// VGPR-capped for 4 waves/SIMD.
__global__ __launch_bounds__(256, 4) void weights_mean(const unsigned short* __restrict__ qh,
                                                       const unsigned short* __restrict__ kh,
                                                       const float* __restrict__ cT,
                                                       float* __restrict__ out1) {
  __shared__ __align__(16) unsigned short Qs[2][64 * 64];
  __shared__ __align__(16) unsigned short Ks[2][64 * 64];
  __shared__ float cL[64 * 16];
  const int tid = threadIdx.x, lane = tid & 63, w = tid >> 6;
  const int lrow = lane & 15, lg = lane >> 4;
  const int n = blockIdx.z;
  const int l0 = blockIdx.y * 64, s0 = blockIdx.x * 64;

  const int sr = tid >> 3;
  const int cs = ((tid & 7) ^ (sr & 7)) * 8;

  // c tile: 64 rows x 16 heads, contiguous at cT[n][l0][0] (4KB)
  ((float4*)cL)[tid] = ((const float4*)(cT + ((size_t)n * LL + l0) * HH))[tid];

  const unsigned short* qp = qh + ((size_t)(n * HH) * LL + l0) * DD;
  const unsigned short* kp = kh + ((size_t)(n * HH) * LL + s0) * DD;
  const size_t hstride = (size_t)LL * DD;   // 128K shorts per head

  gload16(qp + (size_t)sr * DD + cs,        (char*)Qs[0] + tid * 16);
  gload16(qp + (size_t)(sr + 32) * DD + cs, (char*)Qs[0] + tid * 16 + 4096);
  gload16(kp + (size_t)sr * DD + cs,        (char*)Ks[0] + tid * 16);
  gload16(kp + (size_t)(sr + 32) * DD + cs, (char*)Ks[0] + tid * 16 + 4096);
  __syncthreads();

  float accw[4][4] = {};
  const int crow = (w * 16 + lrow) * HH;
  for (int h = 0; h < HH; ++h) {
    const int cur = h & 1;
    if (h + 1 < HH) {      // prefetch next head (drained by end-of-iter barrier)
      const int nxt = cur ^ 1;
      qp += hstride; kp += hstride;
      gload16(qp + (size_t)sr * DD + cs,        (char*)Qs[nxt] + tid * 16);
      gload16(qp + (size_t)(sr + 32) * DD + cs, (char*)Qs[nxt] + tid * 16 + 4096);
      gload16(kp + (size_t)sr * DD + cs,        (char*)Ks[nxt] + tid * 16);
      gload16(kp + (size_t)(sr + 32) * DD + cs, (char*)Ks[nxt] + tid * 16 + 4096);
    }

    short8 qa0 = lds8s(Qs[cur], w * 16 + lrow, lg * 16);
    short8 qa1 = lds8s(Qs[cur], w * 16 + lrow, 64 + lg * 16);
    f32x4 sc[4];
    __builtin_amdgcn_s_setprio(1);
#pragma unroll
    for (int ct = 0; ct < 4; ++ct) {
      short8 b0 = lds8s(Ks[cur], ct * 16 + lrow, lg * 16);
      short8 b1 = lds8s(Ks[cur], ct * 16 + lrow, 64 + lg * 16);
      f32x4 a = {};
      a = __builtin_amdgcn_mfma_f32_16x16x32_bf16(b0, qa0, a, 0, 0, 0);
      a = __builtin_amdgcn_mfma_f32_16x16x32_bf16(b1, qa1, a, 0, 0, 0);
      sc[ct] = a;
    }
    __builtin_amdgcn_s_setprio(0);

    const float c = cL[crow + h];
#pragma unroll
    for (int ct = 0; ct < 4; ++ct)
#pragma unroll
      for (int r = 0; r < 4; ++r)
        accw[ct][r] += __builtin_exp2f(__builtin_fmaf(sc[ct][r], SC2, c));
    __syncthreads();   // prefetch landed; buf[cur] reads done before next overwrite
  }

  const int lt = l0 + w * 16 + lrow;
#pragma unroll
  for (int ct = 0; ct < 4; ++ct) {
    float4 o;
    o.x = accw[ct][0] * 0.0625f;
    o.y = accw[ct][1] * 0.0625f;
    o.z = accw[ct][2] * 0.0625f;
    o.w = accw[ct][3] * 0.0625f;
    *(float4*)&out1[((size_t)n * LL + lt) * LL + s0 + ct * 16 + lg * 4] = o;
  }
}

// ---------- launch ----------
extern "C" void kernel_launch(void* const* d_in, const int* in_sizes, int n_in,
                              void* d_out, int out_size, void* d_ws, size_t ws_size,
                              hipStream_t stream) {
  const float* query = (const float*)d_in[0];
  const float* key   = (const float*)d_in[1];
  const float* value = (const float*)d_in[2];
  const float* Wq = (const float*)d_in[3];
  const float* bq = (const float*)d_in[4];
  const float* Wk = (const float*)d_in[5];
  const float* bk = (const float*)d_in[6];
  const float* Wv = (const float*)d_in[7];
  const float* bv = (const float*)d_in[8];
  const float* Wo = (const float*)d_in[9];
  const float* bo = (const float*)d_in[10];

  float* out0 = (float*)d_out;                       // [2048,4,1024]
  float* out1 = out0 + (size_t)LL * NB * EE;         // [4,2048,2048]

  char* ws = (char*)d_ws;
  unsigned short* xbuf = (unsigned short*)(ws + 0);          // 16 MB, reused; also oh
  unsigned short* wqb  = (unsigned short*)(ws + 16777216);   // 2 MB each
  unsigned short* wkb  = (unsigned short*)(ws + 18874368);
  unsigned short* wvb  = (unsigned short*)(ws + 20971520);
  unsigned short* wob  = (unsigned short*)(ws + 23068672);
  unsigned short* qhb  = (unsigned short*)(ws + 25165824);   // 16 MB
  unsigned short* khb  = (unsigned short*)(ws + 41943040);   // 16 MB
  unsigned short* vthb = (unsigned short*)(ws + 58720256);   // 16 MB
  float* mbuf = (float*)(ws + 75497472);                     // 512 KB
  float* zbuf = (float*)(ws + 76021760);                     // 512 KB
  float* cT   = (float*)(ws + 76546048);                     // 512 KB [n][l][h]

  const int nTok = MROWS * EE;    // 8,388,608
  const int nW   = EE * EE;       // 1,048,576

  conv_bf16<<<nW / 1024, 256, 0, stream>>>(Wq, wqb);
  conv_bf16<<<nW / 1024, 256, 0, stream>>>(Wk, wkb);
  conv_bf16<<<nW / 1024, 256, 0, stream>>>(Wv, wvb);
  conv_bf16<<<nW / 1024, 256, 0, stream>>>(Wo, wob);

  dim3 ggrid(EE / 128, MROWS / 128);  // (8, 64)

  conv_bf16<<<nTok / 1024, 256, 0, stream>>>(query, xbuf);
  gemm_bt<0><<<ggrid, 256, 0, stream>>>(xbuf, wqb, bq, qhb, nullptr);
  conv_bf16<<<nTok / 1024, 256, 0, stream>>>(key, xbuf);
  gemm_bt<0><<<ggrid, 256, 0, stream>>>(xbuf, wkb, bk, khb, nullptr);
  conv_bf16<<<nTok / 1024, 256, 0, stream>>>(value, xbuf);
  gemm_bt<1><<<ggrid, 256, 0, stream>>>(xbuf, wvb, bv, vthb, nullptr);

  flash_attn<<<dim3(LL / 64, NB * HH), 256, 0, stream>>>(qhb, khb, vthb, xbuf, mbuf, zbuf);

  gemm_bt<2><<<ggrid, 256, 0, stream>>>(xbuf, wob, bo, nullptr, out0);

  mz_prep<<<(NB * HH * LL) / 256, 256, 0, stream>>>(mbuf, zbuf, cT);

  weights_mean<<<dim3(LL / 64, LL / 64, NB), 256, 0, stream>>>(qhb, khb, cT, out1);
}

// Round 5
// 554.723 us; speedup vs baseline: 2.1469x; 2.1469x over previous
//
#include <hip/hip_runtime.h>
#include <hip/hip_bf16.h>

// ---------- types & helpers ----------
typedef __attribute__((ext_vector_type(8))) short short8;   // 8 bf16 (4 VGPRs)
typedef __attribute__((ext_vector_type(4))) float f32x4;

#define AS1 __attribute__((address_space(1)))
#define AS3 __attribute__((address_space(3)))

__device__ __forceinline__ void gload16(const void* g, void* l) {
  __builtin_amdgcn_global_load_lds((const AS1 unsigned int*)g,
                                   (AS3 unsigned int*)l, 16, 0, 0);
}

__device__ __forceinline__ unsigned short f2bf(float x) {
  unsigned u = __float_as_uint(x);
  u = (u + 0x7FFFu + ((u >> 16) & 1u)) >> 16;  // RNE
  return (unsigned short)u;
}

__device__ __forceinline__ short8 lds8(const unsigned short* p) {
  return *(const short8*)p;
}

// Swizzled 16B LDS read: logical (row, byteInRow) of a 128B-row tile.
// Swizzle: 16B-slot ^= row&7.
__device__ __forceinline__ short8 lds8s(const unsigned short* base, int row, int byteInRow) {
  const int a = (row << 7) + (byteInRow ^ ((row & 7) << 4));
  return *(const short8*)((const char*)base + a);
}

// Problem constants: L=S=2048, N=4, E=1024, H=16, D=64; rows = L*N = 8192
#define LL 2048
#define NB 4
#define EE 1024
#define HH 16
#define DD 64
#define MROWS 8192
#define SC2 0.18033688f  // 0.125 * log2(e): softmax in exp2 domain

// ---------- fp32 -> bf16 convert ----------
__global__ __launch_bounds__(256) void conv_bf16(const float* __restrict__ src,
                                                 unsigned short* __restrict__ dst) {
  int i = blockIdx.x * 256 + threadIdx.x;
  float4 v = ((const float4*)src)[i];
  ushort4 o;
  o.x = f2bf(v.x); o.y = f2bf(v.y); o.z = f2bf(v.z); o.w = f2bf(v.w);
  ((ushort4*)dst)[i] = o;
}

// ---------- GEMM: C[8192,1024] = A[8192,1024] * B[1024,1024]^T + bias ----------
// MODE 0: bf16 head layout [n,h,l,d]; MODE 1: bf16 transposed [n,h,d,s]; MODE 2: fp32 rows
template <int MODE>
__global__ __launch_bounds__(256) void gemm_bt(const unsigned short* __restrict__ A,
                                               const unsigned short* __restrict__ B,
                                               const float* __restrict__ bias,
                                               unsigned short* __restrict__ outb,
                                               float* __restrict__ outf) {
  constexpr int K = 1024;
  __shared__ __align__(16) unsigned short As[128 * 32];
  __shared__ __align__(16) unsigned short Bs[128 * 32];
  const int tid = threadIdx.x;
  const int lane = tid & 63, w = tid >> 6;
  const int wr = w >> 1, wc = w & 1;           // 2x2 waves, each 64x64
  const int lrow = lane & 15, lg = lane >> 4;
  const int m0 = blockIdx.y * 128, n0 = blockIdx.x * 128;

  f32x4 acc[4][4] = {};

  const int srow = tid >> 2, sseg = tid & 3;   // staging map: 64 rows x 4 16B-segs
  for (int k0 = 0; k0 < K; k0 += 32) {
    __syncthreads();
    const unsigned short* ga = A + (size_t)(m0 + srow) * K + k0 + sseg * 8;
    gload16(ga,            (char*)As + tid * 16);
    gload16(ga + 64 * K,   (char*)As + tid * 16 + 4096);
    const unsigned short* gb = B + (size_t)(n0 + srow) * K + k0 + sseg * 8;
    gload16(gb,            (char*)Bs + tid * 16);
    gload16(gb + 64 * K,   (char*)Bs + tid * 16 + 4096);
    __syncthreads();

    short8 af[4], bf[4];
#pragma unroll
    for (int mt = 0; mt < 4; ++mt)
      af[mt] = lds8(As + (wr * 64 + mt * 16 + lrow) * 32 + lg * 8);
#pragma unroll
    for (int nt = 0; nt < 4; ++nt)
      bf[nt] = lds8(Bs + (wc * 64 + nt * 16 + lrow) * 32 + lg * 8);
#pragma unroll
    for (int mt = 0; mt < 4; ++mt)
#pragma unroll
      for (int nt = 0; nt < 4; ++nt)
        acc[mt][nt] = __builtin_amdgcn_mfma_f32_16x16x32_bf16(af[mt], bf[nt],
                                                              acc[mt][nt], 0, 0, 0);
  }

#pragma unroll
  for (int mt = 0; mt < 4; ++mt) {
#pragma unroll
    for (int nt = 0; nt < 4; ++nt) {
      const int col = n0 + wc * 64 + nt * 16 + lrow;
      const float bv = bias[col];
#pragma unroll
      for (int r = 0; r < 4; ++r) {
        const int row = m0 + wr * 64 + mt * 16 + lg * 4 + r;  // token-row = l*4+n
        const float v = acc[mt][nt][r] + bv;
        if (MODE == 0) {
          const int l = row >> 2, n = row & 3, h = col >> 6, d = col & 63;
          outb[(((size_t)(n * HH + h)) * LL + l) * DD + d] = f2bf(v);
        } else if (MODE == 1) {
          const int s = row >> 2, n = row & 3, h = col >> 6, d = col & 63;
          outb[(((size_t)(n * HH + h)) * DD + d) * LL + s] = f2bf(v);
        } else {
          outf[(size_t)row * EE + col] = v;
        }
      }
    }
  }
}

// ---------- flash attention per (n,h): 64 q-rows per block ----------
// Swapped-operand MFMA: S^T = mfma(K,Q) puts per-lane q = lane&15 -> in-register
// softmax (2 shfls), vector P writes, O^T = mfma(V,P) matches per-lane m/z.
__global__ __launch_bounds__(256) void flash_attn(const unsigned short* __restrict__ qh,
                                                  const unsigned short* __restrict__ kh,
                                                  const unsigned short* __restrict__ vth,
                                                  unsigned short* __restrict__ oh,
                                                  float* __restrict__ mbuf,
                                                  float* __restrict__ zbuf) {
  __shared__ __align__(16) unsigned short Ks[2][64 * 64];
  __shared__ __align__(16) unsigned short Vts[2][64 * 64];
  __shared__ __align__(16) unsigned short QPs[64 * 64];  // Q tile, then reused as P tile
  const int tid = threadIdx.x, lane = tid & 63, w = tid >> 6;
  const int lrow = lane & 15, lg = lane >> 4;
  const int nh = blockIdx.y;
  const int l0 = blockIdx.x * 64;

  const unsigned short* qbase = qh + ((size_t)nh * LL + l0) * DD;
  const unsigned short* kbase = kh + (size_t)nh * LL * DD;
  const unsigned short* vbase = vth + (size_t)nh * DD * LL;

  const int sr = tid >> 3;                      // staging row 0..31 (and +32)
  const int cs = ((tid & 7) ^ (sr & 7)) * 8;    // pre-swizzled col (shorts)

  // stage Q + tile 0 of K/V
  gload16(qbase + (size_t)sr * DD + cs,        (char*)QPs + tid * 16);
  gload16(qbase + (size_t)(sr + 32) * DD + cs, (char*)QPs + tid * 16 + 4096);
  gload16(kbase + (size_t)sr * DD + cs,        (char*)Ks[0] + tid * 16);
  gload16(kbase + (size_t)(sr + 32) * DD + cs, (char*)Ks[0] + tid * 16 + 4096);
  gload16(vbase + (size_t)sr * LL + cs,        (char*)Vts[0] + tid * 16);
  gload16(vbase + (size_t)(sr + 32) * LL + cs, (char*)Vts[0] + tid * 16 + 4096);
  __syncthreads();

  // Q fragments -> registers; QPs rows (wave-private w*16..w*16+15) then free for P
  short8 qa0 = lds8s(QPs, w * 16 + lrow, lg * 16);
  short8 qa1 = lds8s(QPs, w * 16 + lrow, 64 + lg * 16);

  float mrow = -1e30f, zrow = 0.f;   // per-lane: this lane's q-row = l0 + w*16 + lrow
  f32x4 acco[4] = {};                // O[q=lrow][d = dt*16 + lg*4 + r]

  const int prow = w * 16 + lrow;
  int cur = 0;
  for (int s0 = 0; s0 < LL; s0 += 64) {
    // prefetch next K/V tile (overlaps compute; drained by end-of-iter barrier)
    if (s0 + 64 < LL) {
      const int nxt = cur ^ 1;
      const unsigned short* kt = kbase + (size_t)(s0 + 64) * DD;
      gload16(kt + (size_t)sr * DD + cs,        (char*)Ks[nxt] + tid * 16);
      gload16(kt + (size_t)(sr + 32) * DD + cs, (char*)Ks[nxt] + tid * 16 + 4096);
      gload16(vbase + (size_t)sr * LL + (s0 + 64) + cs,        (char*)Vts[nxt] + tid * 16);
      gload16(vbase + (size_t)(sr + 32) * LL + (s0 + 64) + cs, (char*)Vts[nxt] + tid * 16 + 4096);
    }

    // QK^T swapped: sc[ct] = S[q=lrow][k = ct*16 + lg*4 + r]
    f32x4 sc[4];
    __builtin_amdgcn_s_setprio(1);
#pragma unroll
    for (int ct = 0; ct < 4; ++ct) {
      short8 b0 = lds8s(Ks[cur], ct * 16 + lrow, lg * 16);
      short8 b1 = lds8s(Ks[cur], ct * 16 + lrow, 64 + lg * 16);
      f32x4 a = {};
      a = __builtin_amdgcn_mfma_f32_16x16x32_bf16(b0, qa0, a, 0, 0, 0);
      a = __builtin_amdgcn_mfma_f32_16x16x32_bf16(b1, qa1, a, 0, 0, 0);
      sc[ct] = a;
    }
    __builtin_amdgcn_s_setprio(0);

    // in-register row max (this lane's q) + 2 cross-lane shfls
    float t = sc[0][0];
#pragma unroll
    for (int ct = 0; ct < 4; ++ct)
#pragma unroll
      for (int r = 0; r < 4; ++r) t = fmaxf(t, sc[ct][r]);
    t = fmaxf(t, __shfl_xor(t, 16));
    t = fmaxf(t, __shfl_xor(t, 32));
    const float tm = t * SC2;

    if (__any(tm > mrow + 8.0f)) {     // deferred rescale
      const float mnew = fmaxf(mrow, tm);
      const float f = __builtin_exp2f(mrow - mnew);
      mrow = mnew;
      zrow *= f;
#pragma unroll
      for (int dt = 0; dt < 4; ++dt)
#pragma unroll
        for (int r = 0; r < 4; ++r) acco[dt][r] *= f;
    }

    // P = exp2(sc*SC2 - m); pack 4 bf16 per ct; one ds_write_b64 per ct
    float ps = 0.f;
    unsigned int pk[8];
#pragma unroll
    for (int ct = 0; ct < 4; ++ct) {
      float e[4];
#pragma unroll
      for (int r = 0; r < 4; ++r) {
        e[r] = __builtin_exp2f(__builtin_fmaf(sc[ct][r], SC2, -mrow));
        ps += e[r];
      }
      pk[ct * 2 + 0] = (unsigned int)f2bf(e[0]) | ((unsigned int)f2bf(e[1]) << 16);
      pk[ct * 2 + 1] = (unsigned int)f2bf(e[2]) | ((unsigned int)f2bf(e[3]) << 16);
    }
    ps += __shfl_xor(ps, 16);
    ps += __shfl_xor(ps, 32);
    zrow += ps;

#pragma unroll
    for (int ct = 0; ct < 4; ++ct) {
      const int a = (prow << 7) + ((((ct * 2 + (lg >> 1)) ^ (prow & 7)) << 4) | ((lg & 1) << 3));
      uint2 u; u.x = pk[ct * 2]; u.y = pk[ct * 2 + 1];
      *(uint2*)((char*)QPs + a) = u;
    }

    // PV swapped: acco[dt] += Vt_frag · P_frag  (O^T: q = lane&15 matches m/z)
    short8 pa0 = lds8s(QPs, prow, lg * 16);
    short8 pa1 = lds8s(QPs, prow, 64 + lg * 16);
    __builtin_amdgcn_s_setprio(1);
#pragma unroll
    for (int dt = 0; dt < 4; ++dt) {
      short8 vb0 = lds8s(Vts[cur], dt * 16 + lrow, lg * 16);
      short8 vb1 = lds8s(Vts[cur], dt * 16 + lrow, 64 + lg * 16);
      acco[dt] = __builtin_amdgcn_mfma_f32_16x16x32_bf16(vb0, pa0, acco[dt], 0, 0, 0);
      acco[dt] = __builtin_amdgcn_mfma_f32_16x16x32_bf16(vb1, pa1, acco[dt], 0, 0, 0);
    }
    __builtin_amdgcn_s_setprio(0);
    __syncthreads();   // staging drained + all reads of buf[cur] complete
    cur ^= 1;
  }

  const int n = nh >> 4, h = nh & 15;
  const int lt = l0 + w * 16 + lrow;
  const float rz = 1.0f / zrow;
#pragma unroll
  for (int dt = 0; dt < 4; ++dt) {
    ushort4 o;
    o.x = f2bf(acco[dt][0] * rz);
    o.y = f2bf(acco[dt][1] * rz);
    o.z = f2bf(acco[dt][2] * rz);
    o.w = f2bf(acco[dt][3] * rz);
    *(ushort4*)&oh[((size_t)lt * NB + n) * EE + h * 64 + dt * 16 + lg * 4] = o;
  }
  if (lg == 0) {
    mbuf[(size_t)nh * LL + lt] = mrow;   // exp2-domain running max
    zbuf[(size_t)nh * LL + lt] = zrow;
  }
}

// ---------- prep: cT[n][lt][h] = -(m + log2(z))  (weight = exp2(sc*SC2 + c)) ----------
__global__ __launch_bounds__(256) void mz_prep(const float* __restrict__ mbuf,
                                               const float* __restrict__ zbuf,
                                               float* __restrict__ cT) {
  const int i = blockIdx.x * 256 + threadIdx.x;   // over 64*2048
  const int nh = i >> 11, lt = i & 2047;
  const int n = nh >> 4, h = nh & 15;
  const float c = -(mbuf[i] + __builtin_log2f(zbuf[i]));
  cT[((size_t)n * LL + lt) * HH + h] = c;
}

// ---------- weights mean: out1[n][l][s] = (1/16) sum_h exp2(sc*SC2 + c_h) ----------
// Swapped QK^T, double-buffered heads via pointer-stride, c-tile in LDS
// (transposed [h][row] for conflict-free reads). NO waves/EU cap (R4's cap
// at 64 VGPR caused catastrophic scratch spill: 1.77 GB writes).
__global__ __launch_bounds__(256) void weights_mean(const unsigned short* __restrict__ qh,
                                                    const unsigned short* __restrict__ kh,
                                                    const float* __restrict__ cT,
                                                    float* __restrict__ out1) {
  __shared__ __align__(16) unsigned short Qs[2][64 * 64];
  __shared__ __align__(16) unsigned short Ks[2][64 * 64];
  __shared__ float cL[HH * 64];   // [h][row]
  const int tid = threadIdx.x, lane = tid & 63, w = tid >> 6;
  const int lrow = lane & 15, lg = lane >> 4;
  const int n = blockIdx.z;
  const int l0 = blockIdx.y * 64, s0 = blockIdx.x * 64;

  const int sr = tid >> 3;
  const int cs = ((tid & 7) ^ (sr & 7)) * 8;

  // c tile: transpose [64 rows][16 h] (contiguous at cT[n][l0][0]) -> cL[h][row]
  {
    const float* csrc = cT + ((size_t)n * LL + l0) * HH;
#pragma unroll
    for (int j = 0; j < 4; ++j) {
      const int i = tid * 4 + j;               // i over 1024
      const int row = i >> 4, h = i & 15;
      cL[h * 64 + row] = csrc[i];
    }
  }

  const unsigned short* qp = qh + ((size_t)(n * HH) * LL + l0) * DD;
  const unsigned short* kp = kh + ((size_t)(n * HH) * LL + s0) * DD;
  const size_t hstride = (size_t)LL * DD;   // 128K shorts per head

  gload16(qp + (size_t)sr * DD + cs,        (char*)Qs[0] + tid * 16);
  gload16(qp + (size_t)(sr + 32) * DD + cs, (char*)Qs[0] + tid * 16 + 4096);
  gload16(kp + (size_t)sr * DD + cs,        (char*)Ks[0] + tid * 16);
  gload16(kp + (size_t)(sr + 32) * DD + cs, (char*)Ks[0] + tid * 16 + 4096);
  __syncthreads();

  float accw[4][4] = {};
  const int myrow = w * 16 + lrow;
  for (int h = 0; h < HH; ++h) {
    const int cur = h & 1;
    if (h + 1 < HH) {      // prefetch next head (drained by end-of-iter barrier)
      const int nxt = cur ^ 1;
      qp += hstride; kp += hstride;
      gload16(qp + (size_t)sr * DD + cs,        (char*)Qs[nxt] + tid * 16);
      gload16(qp + (size_t)(sr + 32) * DD + cs, (char*)Qs[nxt] + tid * 16 + 4096);
      gload16(kp + (size_t)sr * DD + cs,        (char*)Ks[nxt] + tid * 16);
      gload16(kp + (size_t)(sr + 32) * DD + cs, (char*)Ks[nxt] + tid * 16 + 4096);
    }

    short8 qa0 = lds8s(Qs[cur], myrow, lg * 16);
    short8 qa1 = lds8s(Qs[cur], myrow, 64 + lg * 16);
    f32x4 sc[4];
    __builtin_amdgcn_s_setprio(1);
#pragma unroll
    for (int ct = 0; ct < 4; ++ct) {
      short8 b0 = lds8s(Ks[cur], ct * 16 + lrow, lg * 16);
      short8 b1 = lds8s(Ks[cur], ct * 16 + lrow, 64 + lg * 16);
      f32x4 a = {};
      a = __builtin_amdgcn_mfma_f32_16x16x32_bf16(b0, qa0, a, 0, 0, 0);
      a = __builtin_amdgcn_mfma_f32_16x16x32_bf16(b1, qa1, a, 0, 0, 0);
      sc[ct] = a;
    }
    __builtin_amdgcn_s_setprio(0);

    const float c = cL[h * 64 + myrow];   // lanes 0-15 consecutive: conflict-free
#pragma unroll
    for (int ct = 0; ct < 4; ++ct)
#pragma unroll
      for (int r = 0; r < 4; ++r)
        accw[ct][r] += __builtin_exp2f(__builtin_fmaf(sc[ct][r], SC2, c));
    __syncthreads();   // prefetch landed; buf[cur] reads done before next overwrite
  }

  const int lt = l0 + myrow;
#pragma unroll
  for (int ct = 0; ct < 4; ++ct) {
    float4 o;
    o.x = accw[ct][0] * 0.0625f;
    o.y = accw[ct][1] * 0.0625f;
    o.z = accw[ct][2] * 0.0625f;
    o.w = accw[ct][3] * 0.0625f;
    *(float4*)&out1[((size_t)n * LL + lt) * LL + s0 + ct * 16 + lg * 4] = o;
  }
}

// ---------- launch ----------
extern "C" void kernel_launch(void* const* d_in, const int* in_sizes, int n_in,
                              void* d_out, int out_size, void* d_ws, size_t ws_size,
                              hipStream_t stream) {
  const float* query = (const float*)d_in[0];
  const float* key   = (const float*)d_in[1];
  const float* value = (const float*)d_in[2];
  const float* Wq = (const float*)d_in[3];
  const float* bq = (const float*)d_in[4];
  const float* Wk = (const float*)d_in[5];
  const float* bk = (const float*)d_in[6];
  const float* Wv = (const float*)d_in[7];
  const float* bv = (const float*)d_in[8];
  const float* Wo = (const float*)d_in[9];
  const float* bo = (const float*)d_in[10];

  float* out0 = (float*)d_out;                       // [2048,4,1024]
  float* out1 = out0 + (size_t)LL * NB * EE;         // [4,2048,2048]

  char* ws = (char*)d_ws;
  unsigned short* xbuf = (unsigned short*)(ws + 0);          // 16 MB, reused; also oh
  unsigned short* wqb  = (unsigned short*)(ws + 16777216);   // 2 MB each
  unsigned short* wkb  = (unsigned short*)(ws + 18874368);
  unsigned short* wvb  = (unsigned short*)(ws + 20971520);
  unsigned short* wob  = (unsigned short*)(ws + 23068672);
  unsigned short* qhb  = (unsigned short*)(ws + 25165824);   // 16 MB
  unsigned short* khb  = (unsigned short*)(ws + 41943040);   // 16 MB
  unsigned short* vthb = (unsigned short*)(ws + 58720256);   // 16 MB
  float* mbuf = (float*)(ws + 75497472);                     // 512 KB
  float* zbuf = (float*)(ws + 76021760);                     // 512 KB
  float* cT   = (float*)(ws + 76546048);                     // 512 KB [n][l][h]

  const int nTok = MROWS * EE;    // 8,388,608
  const int nW   = EE * EE;       // 1,048,576

  conv_bf16<<<nW / 1024, 256, 0, stream>>>(Wq, wqb);
  conv_bf16<<<nW / 1024, 256, 0, stream>>>(Wk, wkb);
  conv_bf16<<<nW / 1024, 256, 0, stream>>>(Wv, wvb);
  conv_bf16<<<nW / 1024, 256, 0, stream>>>(Wo, wob);

  dim3 ggrid(EE / 128, MROWS / 128);  // (8, 64)

  conv_bf16<<<nTok / 1024, 256, 0, stream>>>(query, xbuf);
  gemm_bt<0><<<ggrid, 256, 0, stream>>>(xbuf, wqb, bq, qhb, nullptr);
  conv_bf16<<<nTok / 1024, 256, 0, stream>>>(key, xbuf);
  gemm_bt<0><<<ggrid, 256, 0, stream>>>(xbuf, wkb, bk, khb, nullptr);
  conv_bf16<<<nTok / 1024, 256, 0, stream>>>(value, xbuf);
  gemm_bt<1><<<ggrid, 256, 0, stream>>>(xbuf, wvb, bv, vthb, nullptr);

  flash_attn<<<dim3(LL / 64, NB * HH), 256, 0, stream>>>(qhb, khb, vthb, xbuf, mbuf, zbuf);

  gemm_bt<2><<<ggrid, 256, 0, stream>>>(xbuf, wob, bo, nullptr, out0);

  mz_prep<<<(NB * HH * LL) / 256, 256, 0, stream>>>(mbuf, zbuf, cT);

  weights_mean<<<dim3(LL / 64, LL / 64, NB), 256, 0, stream>>>(qhb, khb, cT, out1);
}

// Round 6
// 553.708 us; speedup vs baseline: 2.1508x; 1.0018x over previous
//
#include <hip/hip_runtime.h>
#include <hip/hip_bf16.h>

// ---------- types & helpers ----------
typedef __attribute__((ext_vector_type(8))) short short8;   // 8 bf16 (4 VGPRs)
typedef __attribute__((ext_vector_type(4))) float f32x4;

#define AS1 __attribute__((address_space(1)))
#define AS3 __attribute__((address_space(3)))

__device__ __forceinline__ void gload16(const void* g, void* l) {
  __builtin_amdgcn_global_load_lds((const AS1 unsigned int*)g,
                                   (AS3 unsigned int*)l, 16, 0, 0);
}

__device__ __forceinline__ unsigned short f2bf(float x) {
  unsigned u = __float_as_uint(x);
  u = (u + 0x7FFFu + ((u >> 16) & 1u)) >> 16;  // RNE
  return (unsigned short)u;
}

__device__ __forceinline__ short8 lds8(const unsigned short* p) {
  return *(const short8*)p;
}

// Swizzled 16B LDS read: logical (row, byteInRow) of a 128B-row tile.
// Swizzle: 16B-slot ^= row&7.
__device__ __forceinline__ short8 lds8s(const unsigned short* base, int row, int byteInRow) {
  const int a = (row << 7) + (byteInRow ^ ((row & 7) << 4));
  return *(const short8*)((const char*)base + a);
}

// Problem constants: L=S=2048, N=4, E=1024, H=16, D=64; rows = L*N = 8192
#define LL 2048
#define NB 4
#define EE 1024
#define HH 16
#define DD 64
#define MROWS 8192
#define SC2 0.18033688f  // 0.125 * log2(e): softmax in exp2 domain

// ---------- fp32 -> bf16 convert ----------
__global__ __launch_bounds__(256) void conv_bf16(const float* __restrict__ src,
                                                 unsigned short* __restrict__ dst) {
  int i = blockIdx.x * 256 + threadIdx.x;
  float4 v = ((const float4*)src)[i];
  ushort4 o;
  o.x = f2bf(v.x); o.y = f2bf(v.y); o.z = f2bf(v.z); o.w = f2bf(v.w);
  ((ushort4*)dst)[i] = o;
}

// ---------- GEMM: C[8192,1024] = A[8192,1024] * B[1024,1024]^T + bias ----------
// MODE 0: bf16 head layout [n,h,l,d]; MODE 1: bf16 transposed [n,h,d,s]; MODE 2: fp32 rows
template <int MODE>
__global__ __launch_bounds__(256) void gemm_bt(const unsigned short* __restrict__ A,
                                               const unsigned short* __restrict__ B,
                                               const float* __restrict__ bias,
                                               unsigned short* __restrict__ outb,
                                               float* __restrict__ outf) {
  constexpr int K = 1024;
  __shared__ __align__(16) unsigned short As[128 * 32];
  __shared__ __align__(16) unsigned short Bs[128 * 32];
  const int tid = threadIdx.x;
  const int lane = tid & 63, w = tid >> 6;
  const int wr = w >> 1, wc = w & 1;           // 2x2 waves, each 64x64
  const int lrow = lane & 15, lg = lane >> 4;
  const int m0 = blockIdx.y * 128, n0 = blockIdx.x * 128;

  f32x4 acc[4][4] = {};

  const int srow = tid >> 2, sseg = tid & 3;   // staging map: 64 rows x 4 16B-segs
  for (int k0 = 0; k0 < K; k0 += 32) {
    __syncthreads();
    const unsigned short* ga = A + (size_t)(m0 + srow) * K + k0 + sseg * 8;
    gload16(ga,            (char*)As + tid * 16);
    gload16(ga + 64 * K,   (char*)As + tid * 16 + 4096);
    const unsigned short* gb = B + (size_t)(n0 + srow) * K + k0 + sseg * 8;
    gload16(gb,            (char*)Bs + tid * 16);
    gload16(gb + 64 * K,   (char*)Bs + tid * 16 + 4096);
    __syncthreads();

    short8 af[4], bf[4];
#pragma unroll
    for (int mt = 0; mt < 4; ++mt)
      af[mt] = lds8(As + (wr * 64 + mt * 16 + lrow) * 32 + lg * 8);
#pragma unroll
    for (int nt = 0; nt < 4; ++nt)
      bf[nt] = lds8(Bs + (wc * 64 + nt * 16 + lrow) * 32 + lg * 8);
#pragma unroll
    for (int mt = 0; mt < 4; ++mt)
#pragma unroll
      for (int nt = 0; nt < 4; ++nt)
        acc[mt][nt] = __builtin_amdgcn_mfma_f32_16x16x32_bf16(af[mt], bf[nt],
                                                              acc[mt][nt], 0, 0, 0);
  }

#pragma unroll
  for (int mt = 0; mt < 4; ++mt) {
#pragma unroll
    for (int nt = 0; nt < 4; ++nt) {
      const int col = n0 + wc * 64 + nt * 16 + lrow;
      const float bv = bias[col];
#pragma unroll
      for (int r = 0; r < 4; ++r) {
        const int row = m0 + wr * 64 + mt * 16 + lg * 4 + r;  // token-row = l*4+n
        const float v = acc[mt][nt][r] + bv;
        if (MODE == 0) {
          const int l = row >> 2, n = row & 3, h = col >> 6, d = col & 63;
          outb[(((size_t)(n * HH + h)) * LL + l) * DD + d] = f2bf(v);
        } else if (MODE == 1) {
          const int s = row >> 2, n = row & 3, h = col >> 6, d = col & 63;
          outb[(((size_t)(n * HH + h)) * DD + d) * LL + s] = f2bf(v);
        } else {
          outf[(size_t)row * EE + col] = v;
        }
      }
    }
  }
}

// ---------- flash attention per (n,h): 64 q-rows per block ----------
// Swapped-operand MFMA: S^T = mfma(K,Q) puts per-lane q = lane&15 -> in-register
// softmax (2 shfls), vector P writes, O^T = mfma(V,P) matches per-lane m/z.
__global__ __launch_bounds__(256) void flash_attn(const unsigned short* __restrict__ qh,
                                                  const unsigned short* __restrict__ kh,
                                                  const unsigned short* __restrict__ vth,
                                                  unsigned short* __restrict__ oh,
                                                  float* __restrict__ mbuf,
                                                  float* __restrict__ zbuf) {
  __shared__ __align__(16) unsigned short Ks[2][64 * 64];
  __shared__ __align__(16) unsigned short Vts[2][64 * 64];
  __shared__ __align__(16) unsigned short QPs[64 * 64];  // Q tile, then reused as P tile
  const int tid = threadIdx.x, lane = tid & 63, w = tid >> 6;
  const int lrow = lane & 15, lg = lane >> 4;
  const int nh = blockIdx.y;
  const int l0 = blockIdx.x * 64;

  const unsigned short* qbase = qh + ((size_t)nh * LL + l0) * DD;
  const unsigned short* kbase = kh + (size_t)nh * LL * DD;
  const unsigned short* vbase = vth + (size_t)nh * DD * LL;

  const int sr = tid >> 3;                      // staging row 0..31 (and +32)
  const int cs = ((tid & 7) ^ (sr & 7)) * 8;    // pre-swizzled col (shorts)

  // stage Q + tile 0 of K/V
  gload16(qbase + (size_t)sr * DD + cs,        (char*)QPs + tid * 16);
  gload16(qbase + (size_t)(sr + 32) * DD + cs, (char*)QPs + tid * 16 + 4096);
  gload16(kbase + (size_t)sr * DD + cs,        (char*)Ks[0] + tid * 16);
  gload16(kbase + (size_t)(sr + 32) * DD + cs, (char*)Ks[0] + tid * 16 + 4096);
  gload16(vbase + (size_t)sr * LL + cs,        (char*)Vts[0] + tid * 16);
  gload16(vbase + (size_t)(sr + 32) * LL + cs, (char*)Vts[0] + tid * 16 + 4096);
  __syncthreads();

  // Q fragments -> registers; QPs rows (wave-private w*16..w*16+15) then free for P
  short8 qa0 = lds8s(QPs, w * 16 + lrow, lg * 16);
  short8 qa1 = lds8s(QPs, w * 16 + lrow, 64 + lg * 16);

  float mrow = -1e30f, zrow = 0.f;   // per-lane: this lane's q-row = l0 + w*16 + lrow
  f32x4 acco[4] = {};                // O[q=lrow][d = dt*16 + lg*4 + r]

  const int prow = w * 16 + lrow;
  int cur = 0;
  for (int s0 = 0; s0 < LL; s0 += 64) {
    // prefetch next K/V tile (overlaps compute; drained by end-of-iter barrier)
    if (s0 + 64 < LL) {
      const int nxt = cur ^ 1;
      const unsigned short* kt = kbase + (size_t)(s0 + 64) * DD;
      gload16(kt + (size_t)sr * DD + cs,        (char*)Ks[nxt] + tid * 16);
      gload16(kt + (size_t)(sr + 32) * DD + cs, (char*)Ks[nxt] + tid * 16 + 4096);
      gload16(vbase + (size_t)sr * LL + (s0 + 64) + cs,        (char*)Vts[nxt] + tid * 16);
      gload16(vbase + (size_t)(sr + 32) * LL + (s0 + 64) + cs, (char*)Vts[nxt] + tid * 16 + 4096);
    }

    // QK^T swapped: sc[ct] = S[q=lrow][k = ct*16 + lg*4 + r]
    f32x4 sc[4];
    __builtin_amdgcn_s_setprio(1);
#pragma unroll
    for (int ct = 0; ct < 4; ++ct) {
      short8 b0 = lds8s(Ks[cur], ct * 16 + lrow, lg * 16);
      short8 b1 = lds8s(Ks[cur], ct * 16 + lrow, 64 + lg * 16);
      f32x4 a = {};
      a = __builtin_amdgcn_mfma_f32_16x16x32_bf16(b0, qa0, a, 0, 0, 0);
      a = __builtin_amdgcn_mfma_f32_16x16x32_bf16(b1, qa1, a, 0, 0, 0);
      sc[ct] = a;
    }
    __builtin_amdgcn_s_setprio(0);

    // in-register row max (this lane's q) + 2 cross-lane shfls
    float t = sc[0][0];
#pragma unroll
    for (int ct = 0; ct < 4; ++ct)
#pragma unroll
      for (int r = 0; r < 4; ++r) t = fmaxf(t, sc[ct][r]);
    t = fmaxf(t, __shfl_xor(t, 16));
    t = fmaxf(t, __shfl_xor(t, 32));
    const float tm = t * SC2;

    if (__any(tm > mrow + 8.0f)) {     // deferred rescale
      const float mnew = fmaxf(mrow, tm);
      const float f = __builtin_exp2f(mrow - mnew);
      mrow = mnew;
      zrow *= f;
#pragma unroll
      for (int dt = 0; dt < 4; ++dt)
#pragma unroll
        for (int r = 0; r < 4; ++r) acco[dt][r] *= f;
    }

    // P = exp2(sc*SC2 - m); pack 4 bf16 per ct; one ds_write_b64 per ct
    float ps = 0.f;
    unsigned int pk[8];
#pragma unroll
    for (int ct = 0; ct < 4; ++ct) {
      float e[4];
#pragma unroll
      for (int r = 0; r < 4; ++r) {
        e[r] = __builtin_exp2f(__builtin_fmaf(sc[ct][r], SC2, -mrow));
        ps += e[r];
      }
      pk[ct * 2 + 0] = (unsigned int)f2bf(e[0]) | ((unsigned int)f2bf(e[1]) << 16);
      pk[ct * 2 + 1] = (unsigned int)f2bf(e[2]) | ((unsigned int)f2bf(e[3]) << 16);
    }
    ps += __shfl_xor(ps, 16);
    ps += __shfl_xor(ps, 32);
    zrow += ps;

#pragma unroll
    for (int ct = 0; ct < 4; ++ct) {
      const int a = (prow << 7) + ((((ct * 2 + (lg >> 1)) ^ (prow & 7)) << 4) | ((lg & 1) << 3));
      uint2 u; u.x = pk[ct * 2]; u.y = pk[ct * 2 + 1];
      *(uint2*)((char*)QPs + a) = u;
    }

    // PV swapped: acco[dt] += Vt_frag · P_frag  (O^T: q = lane&15 matches m/z)
    short8 pa0 = lds8s(QPs, prow, lg * 16);
    short8 pa1 = lds8s(QPs, prow, 64 + lg * 16);
    __builtin_amdgcn_s_setprio(1);
#pragma unroll
    for (int dt = 0; dt < 4; ++dt) {
      short8 vb0 = lds8s(Vts[cur], dt * 16 + lrow, lg * 16);
      short8 vb1 = lds8s(Vts[cur], dt * 16 + lrow, 64 + lg * 16);
      acco[dt] = __builtin_amdgcn_mfma_f32_16x16x32_bf16(vb0, pa0, acco[dt], 0, 0, 0);
      acco[dt] = __builtin_amdgcn_mfma_f32_16x16x32_bf16(vb1, pa1, acco[dt], 0, 0, 0);
    }
    __builtin_amdgcn_s_setprio(0);
    __syncthreads();   // staging drained + all reads of buf[cur] complete
    cur ^= 1;
  }

  const int n = nh >> 4, h = nh & 15;
  const int lt = l0 + w * 16 + lrow;
  const float rz = 1.0f / zrow;
#pragma unroll
  for (int dt = 0; dt < 4; ++dt) {
    ushort4 o;
    o.x = f2bf(acco[dt][0] * rz);
    o.y = f2bf(acco[dt][1] * rz);
    o.z = f2bf(acco[dt][2] * rz);
    o.w = f2bf(acco[dt][3] * rz);
    *(ushort4*)&oh[((size_t)lt * NB + n) * EE + h * 64 + dt * 16 + lg * 4] = o;
  }
  if (lg == 0) {
    mbuf[(size_t)nh * LL + lt] = mrow;   // exp2-domain running max
    zbuf[(size_t)nh * LL + lt] = zrow;
  }
}

// ---------- prep: cT[n][lt][h] = -(m + log2(z))  (weight = exp2(sc*SC2 + c)) ----------
__global__ __launch_bounds__(256) void mz_prep(const float* __restrict__ mbuf,
                                               const float* __restrict__ zbuf,
                                               float* __restrict__ cT) {
  const int i = blockIdx.x * 256 + threadIdx.x;   // over 64*2048
  const int nh = i >> 11, lt = i & 2047;
  const int n = nh >> 4, h = nh & 15;
  const float c = -(mbuf[i] + __builtin_log2f(zbuf[i]));
  cT[((size_t)n * LL + lt) * HH + h] = c;
}

// ---------- weights mean: out1[n][l][s] = (1/16) sum_h exp2(sc*SC2 + c_h) ----------
// Swapped QK^T; 2-deep head prefetch; cL transposed [h][row].
// VGPR-slim: each sc quadrant is consumed by exp2 immediately after its MFMA
// (no sc[16] array, no setprio fence) so live ranges stay short.
__global__ __launch_bounds__(256) void weights_mean(const unsigned short* __restrict__ qh,
                                                    const unsigned short* __restrict__ kh,
                                                    const float* __restrict__ cT,
                                                    float* __restrict__ out1) {
  __shared__ __align__(16) unsigned short Qs[2][64 * 64];
  __shared__ __align__(16) unsigned short Ks[2][64 * 64];
  __shared__ float cL[HH * 64];   // [h][row]
  const int tid = threadIdx.x, lane = tid & 63, w = tid >> 6;
  const int lrow = lane & 15, lg = lane >> 4;
  const int n = blockIdx.z;
  const int l0 = blockIdx.y * 64, s0 = blockIdx.x * 64;

  const int sr = tid >> 3;
  const int cs = ((tid & 7) ^ (sr & 7)) * 8;

  // c tile: transpose [64 rows][16 h] (contiguous at cT[n][l0][0]) -> cL[h][row]
  {
    const float* csrc = cT + ((size_t)n * LL + l0) * HH;
#pragma unroll
    for (int j = 0; j < 4; ++j) {
      const int i = tid * 4 + j;               // i over 1024
      const int row = i >> 4, h = i & 15;
      cL[h * 64 + row] = csrc[i];
    }
  }

  const unsigned short* qp = qh + ((size_t)(n * HH) * LL + l0) * DD;
  const unsigned short* kp = kh + ((size_t)(n * HH) * LL + s0) * DD;
  const size_t hstride = (size_t)LL * DD;   // 128K shorts per head

  gload16(qp + (size_t)sr * DD + cs,        (char*)Qs[0] + tid * 16);
  gload16(qp + (size_t)(sr + 32) * DD + cs, (char*)Qs[0] + tid * 16 + 4096);
  gload16(kp + (size_t)sr * DD + cs,        (char*)Ks[0] + tid * 16);
  gload16(kp + (size_t)(sr + 32) * DD + cs, (char*)Ks[0] + tid * 16 + 4096);
  __syncthreads();

  float accw[4][4] = {};
  const int myrow = w * 16 + lrow;
  for (int h = 0; h < HH; ++h) {
    const int cur = h & 1;
    if (h + 1 < HH) {      // prefetch next head (drained by end-of-iter barrier)
      const int nxt = cur ^ 1;
      qp += hstride; kp += hstride;
      gload16(qp + (size_t)sr * DD + cs,        (char*)Qs[nxt] + tid * 16);
      gload16(qp + (size_t)(sr + 32) * DD + cs, (char*)Qs[nxt] + tid * 16 + 4096);
      gload16(kp + (size_t)sr * DD + cs,        (char*)Ks[nxt] + tid * 16);
      gload16(kp + (size_t)(sr + 32) * DD + cs, (char*)Ks[nxt] + tid * 16 + 4096);
    }

    short8 qa0 = lds8s(Qs[cur], myrow, lg * 16);
    short8 qa1 = lds8s(Qs[cur], myrow, 64 + lg * 16);
    const float c = cL[h * 64 + myrow];   // lanes 0-15 consecutive: conflict-free

#pragma unroll
    for (int ct = 0; ct < 4; ++ct) {
      short8 b0 = lds8s(Ks[cur], ct * 16 + lrow, lg * 16);
      short8 b1 = lds8s(Ks[cur], ct * 16 + lrow, 64 + lg * 16);
      f32x4 a = {};
      a = __builtin_amdgcn_mfma_f32_16x16x32_bf16(b0, qa0, a, 0, 0, 0);
      a = __builtin_amdgcn_mfma_f32_16x16x32_bf16(b1, qa1, a, 0, 0, 0);
      // consume immediately: sc quadrant never stored
#pragma unroll
      for (int r = 0; r < 4; ++r)
        accw[ct][r] += __builtin_exp2f(__builtin_fmaf(a[r], SC2, c));
    }
    __syncthreads();   // prefetch landed; buf[cur] reads done before next overwrite
  }

  const int lt = l0 + myrow;
#pragma unroll
  for (int ct = 0; ct < 4; ++ct) {
    float4 o;
    o.x = accw[ct][0] * 0.0625f;
    o.y = accw[ct][1] * 0.0625f;
    o.z = accw[ct][2] * 0.0625f;
    o.w = accw[ct][3] * 0.0625f;
    *(float4*)&out1[((size_t)n * LL + lt) * LL + s0 + ct * 16 + lg * 4] = o;
  }
}

// ---------- launch ----------
extern "C" void kernel_launch(void* const* d_in, const int* in_sizes, int n_in,
                              void* d_out, int out_size, void* d_ws, size_t ws_size,
                              hipStream_t stream) {
  const float* query = (const float*)d_in[0];
  const float* key   = (const float*)d_in[1];
  const float* value = (const float*)d_in[2];
  const float* Wq = (const float*)d_in[3];
  const float* bq = (const float*)d_in[4];
  const float* Wk = (const float*)d_in[5];
  const float* bk = (const float*)d_in[6];
  const float* Wv = (const float*)d_in[7];
  const float* bv = (const float*)d_in[8];
  const float* Wo = (const float*)d_in[9];
  const float* bo = (const float*)d_in[10];

  float* out0 = (float*)d_out;                       // [2048,4,1024]
  float* out1 = out0 + (size_t)LL * NB * EE;         // [4,2048,2048]

  char* ws = (char*)d_ws;
  unsigned short* xbuf = (unsigned short*)(ws + 0);          // 16 MB, reused; also oh
  unsigned short* wqb  = (unsigned short*)(ws + 16777216);   // 2 MB each
  unsigned short* wkb  = (unsigned short*)(ws + 18874368);
  unsigned short* wvb  = (unsigned short*)(ws + 20971520);
  unsigned short* wob  = (unsigned short*)(ws + 23068672);
  unsigned short* qhb  = (unsigned short*)(ws + 25165824);   // 16 MB
  unsigned short* khb  = (unsigned short*)(ws + 41943040);   // 16 MB
  unsigned short* vthb = (unsigned short*)(ws + 58720256);   // 16 MB
  float* mbuf = (float*)(ws + 75497472);                     // 512 KB
  float* zbuf = (float*)(ws + 76021760);                     // 512 KB
  float* cT   = (float*)(ws + 76546048);                     // 512 KB [n][l][h]

  const int nTok = MROWS * EE;    // 8,388,608
  const int nW   = EE * EE;       // 1,048,576

  conv_bf16<<<nW / 1024, 256, 0, stream>>>(Wq, wqb);
  conv_bf16<<<nW / 1024, 256, 0, stream>>>(Wk, wkb);
  conv_bf16<<<nW / 1024, 256, 0, stream>>>(Wv, wvb);
  conv_bf16<<<nW / 1024, 256, 0, stream>>>(Wo, wob);

  dim3 ggrid(EE / 128, MROWS / 128);  // (8, 64)

  conv_bf16<<<nTok / 1024, 256, 0, stream>>>(query, xbuf);
  gemm_bt<0><<<ggrid, 256, 0, stream>>>(xbuf, wqb, bq, qhb, nullptr);
  conv_bf16<<<nTok / 1024, 256, 0, stream>>>(key, xbuf);
  gemm_bt<0><<<ggrid, 256, 0, stream>>>(xbuf, wkb, bk, khb, nullptr);
  conv_bf16<<<nTok / 1024, 256, 0, stream>>>(value, xbuf);
  gemm_bt<1><<<ggrid, 256, 0, stream>>>(xbuf, wvb, bv, vthb, nullptr);

  flash_attn<<<dim3(LL / 64, NB * HH), 256, 0, stream>>>(qhb, khb, vthb, xbuf, mbuf, zbuf);

  gemm_bt<2><<<ggrid, 256, 0, stream>>>(xbuf, wob, bo, nullptr, out0);

  mz_prep<<<(NB * HH * LL) / 256, 256, 0, stream>>>(mbuf, zbuf, cT);

  weights_mean<<<dim3(LL / 64, LL / 64, NB), 256, 0, stream>>>(qhb, khb, cT, out1);
}